// Round 4
// baseline (331.029 us; speedup 1.0000x reference)
//
#include <hip/hip_runtime.h>
#include <stdint.h>

typedef short s16x8 __attribute__((ext_vector_type(8)));
typedef float f32x4 __attribute__((ext_vector_type(4)));

#define TT 256
#define CC 384
#define HH 64
#define NTOT 192

__device__ __forceinline__ unsigned short f2bf(float f) {
  union { float f; uint32_t u; } v; v.f = f;
  return (unsigned short)((v.u + 0x7fffu + ((v.u >> 16) & 1u)) >> 16);
}

__device__ __forceinline__ void gload_lds16(const void* g, void* l) {
  __builtin_amdgcn_global_load_lds(
      (const __attribute__((address_space(1))) unsigned int*)g,
      (__attribute__((address_space(3))) unsigned int*)l, 16, 0, 0);
}

// k0: prepack W^T bf16 [192 n][384 k] (K cols pre-scaled) + biases f32[192] into ws
__global__ void prepack_kernel(const float* __restrict__ Wv, const float* __restrict__ bv,
                               const float* __restrict__ Wk, const float* __restrict__ bk,
                               const float* __restrict__ Wq, const float* __restrict__ bq,
                               unsigned short* __restrict__ WT, float* __restrict__ biases) {
  const float scale = 0.05103103630798287f;  // 384^-0.5
  int id = blockIdx.x * 256 + threadIdx.x;
  if (id < NTOT * CC) {
    int n = id / CC, k = id % CC;
    int type = n >> 6, h = n & 63;
    const float* W = (type == 0) ? Wk : (type == 1 ? Wq : Wv);
    float v = W[k * HH + h];
    if (type == 0) v *= scale;
    WT[id] = f2bf(v);
  }
  if (id < NTOT) {
    int type = id >> 6, h = id & 63;
    const float* bb = (type == 0) ? bk : (type == 1 ? bq : bv);
    float v = bb[h];
    if (type == 0) v *= scale;
    biases[id] = v;
  }
}

// LDS layout (union, 118784 B total):
//  phase1: inp bufs @0/16384 (16384 each: 256 rows * 64B bf16, unit-XOR swizzle)
//          wt  bufs @32768/48128 (15360 each: 192 rows * 80B, last 16B pad)
//  phase2: K @0, Q @32768, V @65536 (32768 each, XOR swizzle)
//          P  @98304: per-wave 1280 B ([16][40] u16)
__global__ __launch_bounds__(1024, 4) void attn_head_kernel(
    const float* __restrict__ inp, const unsigned short* __restrict__ WT,
    const float* __restrict__ biases, float* __restrict__ out)
{
  __shared__ char lds[118784];

  const int b    = blockIdx.x;
  const int tid  = threadIdx.x;
  const int wave = tid >> 6;
  const int lane = tid & 63;
  const int l15  = lane & 15;
  const int lg   = lane >> 4;
  const int tw   = wave >> 2;   // 0..3: t = tw*64 + ...
  const int nw   = wave & 3;    // 0..3: n = nw*48 + ...

  const float* inp_b = inp + (size_t)b * TT * CC;
  char* inpbuf0 = lds;          char* inpbuf1 = lds + 16384;
  char* wtbuf0  = lds + 32768;  char* wtbuf1  = lds + 48128;

  // ---------------- Phase 1: KQV projection
  f32x4 acc[4][3];
#pragma unroll
  for (int mf = 0; mf < 4; ++mf)
#pragma unroll
    for (int nf = 0; nf < 3; ++nf)
      acc[mf][nf] = (f32x4){0.f, 0.f, 0.f, 0.f};

  const int srow = tid >> 2;        // 0..255
  const int sk8  = (tid & 3) * 8;   // 0/8/16/24
  const int sunit = (tid & 3) ^ ((srow >> 1) & 3);   // swizzled 16B unit in 64B row

  // wt DMA helper values (waves 0..14, 1 issue each: 960 units of 16B)
  const int wg = wave * 64 + lane;            // 0..959
  const int wn = wg / 5;                      // wt row n
  const int wu = wg % 5;                      // 16B unit in 80B row (4 = pad)
  const int wuu = (wu == 4) ? 0 : wu;         // clamp pad's source
  const unsigned short* wsrc_base = WT + wn * CC + wuu * 8;

  float4 r0, r1;
  r0 = *(const float4*)(inp_b + srow * CC + sk8);
  r1 = *(const float4*)(inp_b + srow * CC + sk8 + 4);
  if (wave < 15) gload_lds16(wsrc_base, wtbuf0 + wave * 1024);

  for (int c = 0; c < 12; ++c) {
    char* ib = (c & 1) ? inpbuf1 : inpbuf0;
    char* wb = (c & 1) ? wtbuf1 : wtbuf0;
    asm volatile("s_waitcnt vmcnt(0)" ::: "memory");
    // pack 8 f32 -> bf16, one swizzled b128 write
    {
      union { s16x8 v; unsigned short s[8]; } p;
      p.s[0] = f2bf(r0.x); p.s[1] = f2bf(r0.y); p.s[2] = f2bf(r0.z); p.s[3] = f2bf(r0.w);
      p.s[4] = f2bf(r1.x); p.s[5] = f2bf(r1.y); p.s[6] = f2bf(r1.z); p.s[7] = f2bf(r1.w);
      *(s16x8*)(ib + srow * 64 + sunit * 16) = p.v;
    }
    if (c < 11) {  // prefetch next chunk to regs (latency hides under MFMA below)
      int k0 = (c + 1) * 32;
      r0 = *(const float4*)(inp_b + srow * CC + k0 + sk8);
      r1 = *(const float4*)(inp_b + srow * CC + k0 + sk8 + 4);
    }
    __syncthreads();
    // issue next wt DMA AFTER barrier (prev readers of that buffer are done)
    if (c < 11 && wave < 15)
      gload_lds16(wsrc_base + (c + 1) * 32, ((c & 1) ? wtbuf0 : wtbuf1) + wave * 1024);
    // fragments + MFMA
    s16x8 bb[3];
#pragma unroll
    for (int nf = 0; nf < 3; ++nf) {
      int n = nw * 48 + nf * 16 + l15;
      bb[nf] = *(const s16x8*)(wb + n * 80 + lg * 16);
    }
#pragma unroll
    for (int mf = 0; mf < 4; ++mf) {
      int t = tw * 64 + mf * 16 + l15;
      int unit = lg ^ ((t >> 1) & 3);
      s16x8 a = *(const s16x8*)(ib + t * 64 + unit * 16);
#pragma unroll
      for (int nf = 0; nf < 3; ++nf)
        acc[mf][nf] = __builtin_amdgcn_mfma_f32_16x16x32_bf16(a, bb[nf], acc[mf][nf], 0, 0, 0);
    }
  }

  __syncthreads();   // staging reads done everywhere; KQV region (aliased) writable

  // epilogue: bias add (K pre-scaled), bf16, scatter into swizzled K/Q/V
  {
    char* Kb = lds; char* Qb = lds + 32768; char* Vb = lds + 65536;
    float bias[3];
#pragma unroll
    for (int nf = 0; nf < 3; ++nf) bias[nf] = biases[nw * 48 + nf * 16 + l15];
#pragma unroll
    for (int nf = 0; nf < 3; ++nf) {
      int n = nw * 48 + nf * 16 + l15;
#pragma unroll
      for (int mf = 0; mf < 4; ++mf) {
#pragma unroll
        for (int r = 0; r < 4; ++r) {
          int t = tw * 64 + mf * 16 + lg * 4 + r;   // D layout: row=lg*4+r, col=l15
          unsigned short hv = f2bf(acc[mf][nf][r] + bias[nf]);
          if (n < 64) {
            *(unsigned short*)(Kb + t * 128 + ((n * 2) ^ ((t & 7) << 4))) = hv;
          } else if (n < 128) {
            int nn = n - 64;
            *(unsigned short*)(Qb + t * 128 + ((nn * 2) ^ ((t & 7) << 4))) = hv;
          } else {
            int nn = n - 128;
            *(unsigned short*)(Vb + nn * 512 + ((t * 2) ^ ((nn & 7) << 4))) = hv;
          }
        }
      }
    }
  }
  __syncthreads();

  // ---------------- Phase 2: one 16-row t-frag per wave (per-SIMD balanced table)
  const char* Kb = lds;
  const char* Qb = lds + 32768;
  const char* Vb = lds + 65536;
  char* Pw = lds + 98304 + wave * 1280;   // [16][40] u16 per wave

  {
    const int gi = wave & 3, ii = wave >> 2;
    const int tf = (gi < 2) ? (ii * 2 + (ii >> 1) * 8 + gi) : (4 + ii * 2 + (gi - 2));
    const int t0 = tf * 16;
    float m[4], lsum[4];
    f32x4 O[4];
#pragma unroll
    for (int r = 0; r < 4; ++r) { m[r] = -1e30f; lsum[r] = 0.f; }
#pragma unroll
    for (int nf = 0; nf < 4; ++nf) O[nf] = (f32x4){0.f, 0.f, 0.f, 0.f};

    const int trow = t0 + l15;
    const int swzT = (trow & 7) << 4;

    for (int s0 = 0; s0 < t0 + 16; s0 += 32) {
      f32x4 Sa = {0.f,0.f,0.f,0.f}, Sb = {0.f,0.f,0.f,0.f};
      const int srw = s0 + l15;
      const int swzS = (srw & 7) << 4;
#pragma unroll
      for (int kk = 0; kk < 2; ++kk) {
        int hb = (kk * 32 + lg * 8) * 2;
        s16x8 a  = *(const s16x8*)(Kb + trow * 128 + (hb ^ swzT));
        s16x8 q0 = *(const s16x8*)(Qb + srw * 128 + (hb ^ swzS));
        s16x8 q1 = *(const s16x8*)(Qb + (srw + 16) * 128 + (hb ^ swzS));
        Sa = __builtin_amdgcn_mfma_f32_16x16x32_bf16(a, q0, Sa, 0, 0, 0);
        Sb = __builtin_amdgcn_mfma_f32_16x16x32_bf16(a, q1, Sb, 0, 0, 0);
      }
      float alpha[4], pa[4], pb[4];
#pragma unroll
      for (int r = 0; r < 4; ++r) {
        int t = t0 + lg * 4 + r;
        int sA = s0 + l15;
        float xa = (sA      <= t) ? Sa[r] : -1e30f;
        float xb = (sA + 16 <= t) ? Sb[r] : -1e30f;
        float mx = fmaxf(xa, xb);
#pragma unroll
        for (int d = 1; d < 16; d <<= 1) mx = fmaxf(mx, __shfl_xor(mx, d, 64));
        float mn = fmaxf(m[r], mx);
        alpha[r] = __expf(m[r] - mn);
        m[r] = mn;
        pa[r] = __expf(xa - mn);
        pb[r] = __expf(xb - mn);
        float rs = pa[r] + pb[r];
#pragma unroll
        for (int d = 1; d < 16; d <<= 1) rs += __shfl_xor(rs, d, 64);
        lsum[r] = lsum[r] * alpha[r] + rs;
      }
#pragma unroll
      for (int nf = 0; nf < 4; ++nf)
#pragma unroll
        for (int r = 0; r < 4; ++r) O[nf][r] *= alpha[r];
      // P tile -> wave-private LDS, in-wave fence, reload as A-fragment
#pragma unroll
      for (int r = 0; r < 4; ++r) {
        int prow = lg * 4 + r;
        *(unsigned short*)(Pw + prow * 80 + l15 * 2)      = f2bf(pa[r]);
        *(unsigned short*)(Pw + prow * 80 + l15 * 2 + 32) = f2bf(pb[r]);
      }
      asm volatile("s_waitcnt lgkmcnt(0)" ::: "memory");
      __builtin_amdgcn_sched_barrier(0);
      s16x8 pfrag = *(const s16x8*)(Pw + l15 * 80 + lg * 16);
#pragma unroll
      for (int nf = 0; nf < 4; ++nf) {
        int h = nf * 16 + l15;
        int sbyte = (s0 + lg * 8) * 2;
        s16x8 vb = *(const s16x8*)(Vb + h * 512 + (sbyte ^ ((h & 7) << 4)));
        O[nf] = __builtin_amdgcn_mfma_f32_16x16x32_bf16(pfrag, vb, O[nf], 0, 0, 0);
      }
    }
    float* outb = out + ((size_t)b * TT + t0) * HH;
#pragma unroll
    for (int r = 0; r < 4; ++r) {
      float inv = 1.0f / lsum[r];
#pragma unroll
      for (int nf = 0; nf < 4; ++nf)
        outb[(lg * 4 + r) * HH + nf * 16 + l15] = O[nf][r] * inv;
    }
  }
}

extern "C" void kernel_launch(void* const* d_in, const int* in_sizes, int n_in,
                              void* d_out, int out_size, void* d_ws, size_t ws_size,
                              hipStream_t stream) {
  (void)n_in; (void)out_size; (void)ws_size;
  const float* inp = (const float*)d_in[0];
  const float* Wv  = (const float*)d_in[1];
  const float* bv  = (const float*)d_in[2];
  const float* Wk  = (const float*)d_in[3];
  const float* bk  = (const float*)d_in[4];
  const float* Wq  = (const float*)d_in[5];
  const float* bq  = (const float*)d_in[6];
  float* out = (float*)d_out;

  unsigned short* WT = (unsigned short*)d_ws;              // 147456 B
  float* biases = (float*)((char*)d_ws + NTOT * CC * 2);   // 768 B

  const int B = in_sizes[0] / (TT * CC);   // 512
  prepack_kernel<<<(NTOT * CC + 255) / 256, 256, 0, stream>>>(Wv, bv, Wk, bk, Wq, bq, WT, biases);
  attn_head_kernel<<<B, 1024, 0, stream>>>(inp, WT, biases, out);
}